// Round 3
// baseline (289.711 us; speedup 1.0000x reference)
//
#include <hip/hip_runtime.h>
#include <hip/hip_cooperative_groups.h>

namespace cg = cooperative_groups;

// spec (32, 4000, 161, 2) f32.
//   pow[b,t,k]  = re^2 + im^2
//   g0[b,t]     = sqrt((2*sum(pow) - pow[0] - pow[160]) / 320)
//   gain[b,t]   = EMA over t: c = 0.9c + 0.1*g0  (gain[b,0]=g0[b,0])
//   new_spec    = spec / (gain + 0.001)
// Outputs flat-concat: new_spec (41,216,000 f32) then gain (128,000 f32).

typedef float f32x4 __attribute__((ext_vector_type(4)));
typedef float f32x2 __attribute__((ext_vector_type(2)));

#define B_SZ 32
#define T_SZ 4000
#define FRAME_F 322            // floats per frame (161 bins * 2)
#define FRAMES (B_SZ * T_SZ)   // 128000
#define N_SPEC ((size_t)FRAMES * FRAME_F)  // 41,216,000
#define N4 (N_SPEC / 4)        // 10,304,000 (exact)
#define EMA_W 384              // 0.9^384 ~ 4e-18: below f32 resolution
#define BLOCK 256
#define CHUNKS_PER_B 16        // ceil(4000/256)

__global__ __launch_bounds__(BLOCK, 4) void k_fused(
    const float* __restrict__ spec, float* __restrict__ out,
    float* __restrict__ gain, float* __restrict__ g0) {
  cg::grid_group grid = cg::this_grid();
  __shared__ float xs[EMA_W + 256];

  // ---- Phase 1: per-frame g0; one 64-lane wave per frame, grid-stride ----
  {
    int lane   = threadIdx.x & 63;
    int wave0  = (blockIdx.x * BLOCK + threadIdx.x) >> 6;
    int nwaves = (gridDim.x * BLOCK) >> 6;
    for (int wid = wave0; wid < FRAMES; wid += nwaves) {
      const float* fp = spec + (size_t)wid * FRAME_F;
      f32x4 v0 = *(const f32x4*)(fp + lane * 4);     // pairs 0..127
      float s0 = v0.x * v0.x + v0.y * v0.y;
      float s1 = v0.z * v0.z + v0.w * v0.w;
      float acc = 2.0f * (s0 + s1);
      if (lane == 0) acc -= s0;                      // pow[0] weight 1
      if (lane < 16) {                               // pairs 128..159
        f32x4 v1 = *(const f32x4*)(fp + (64 + lane) * 4);
        acc += 2.0f * (v1.x * v1.x + v1.y * v1.y + v1.z * v1.z + v1.w * v1.w);
      } else if (lane == 16) {                       // pair 160, weight 1
        f32x2 v2 = *(const f32x2*)(fp + 320);
        acc += v2.x * v2.x + v2.y * v2.y;
      }
#pragma unroll
      for (int off = 32; off > 0; off >>= 1) acc += __shfl_xor(acc, off, 64);
      if (lane == 0) g0[wid] = sqrtf(acc * (1.0f / 320.0f));
    }
  }

  grid.sync();

  // ---- Phase 2: EMA via truncated window (exact for t < EMA_W) ----
  for (int u = blockIdx.x; u < B_SZ * CHUNKS_PER_B; u += gridDim.x) {
    int b  = u >> 4;                 // CHUNKS_PER_B == 16
    int t0 = (u & 15) * 256;
    int lo = t0 - (EMA_W - 1); if (lo < 0) lo = 0;
    int hi = t0 + 256; if (hi > T_SZ) hi = T_SZ;     // exclusive
    int n  = hi - lo;
    const float* gb = g0 + b * T_SZ;
    __syncthreads();                                 // xs reuse guard
    for (int i = threadIdx.x; i < n; i += BLOCK) xs[i] = gb[lo + i];
    __syncthreads();
    int t = t0 + (int)threadIdx.x;
    if (t < T_SZ) {
      int s = t - (EMA_W - 1); if (s < 1) s = 1;
      float c = (s == 1) ? xs[0] : 0.f;              // lo==0 whenever s==1
      for (int k = s; k <= t; ++k) c = c * 0.9f + xs[k - lo] * 0.1f;
      gain[b * T_SZ + t] = c;
    }
  }

  grid.sync();

  // ---- Phase 3: out = spec / (gain + 1e-3), flat f32x4 grid-stride ----
  {
    size_t stride = (size_t)gridDim.x * BLOCK;
    for (size_t i = (size_t)blockIdx.x * BLOCK + threadIdx.x; i < N4; i += stride) {
      f32x4 v = ((const f32x4*)spec)[i];
      unsigned p0 = (unsigned)(2 * i);               // pair index of (v.x,v.y)
      unsigned f0 = p0 / 161u;                       // frame ids (magic mul)
      unsigned f1 = (p0 + 1) / 161u;
      float inv0 = 1.0f / (gain[f0] + 0.001f);
      float inv1 = 1.0f / (gain[f1] + 0.001f);
      f32x4 r;
      r.x = v.x * inv0; r.y = v.y * inv0;
      r.z = v.z * inv1; r.w = v.w * inv1;
      // nt store: keep spec resident in Infinity Cache for next replay
      __builtin_nontemporal_store(r, (f32x4*)out + i);
    }
  }
}

extern "C" void kernel_launch(void* const* d_in, const int* in_sizes, int n_in,
                              void* d_out, int out_size, void* d_ws, size_t ws_size,
                              hipStream_t stream) {
  const float* spec = (const float*)d_in[0];
  float* out  = (float*)d_out;
  float* gain = out + N_SPEC;        // gain output lives in the d_out tail
  float* g0   = (float*)d_ws;        // 128000 f32 scratch

  // Co-residency-safe grid for cooperative launch (host-side query only).
  int maxb_per_cu = 4;
  (void)hipOccupancyMaxActiveBlocksPerMultiprocessor(&maxb_per_cu, (const void*)k_fused, BLOCK, 0);
  if (maxb_per_cu < 1) maxb_per_cu = 1;
  int grid = maxb_per_cu * 256;
  if (grid > 1024) grid = 1024;

  void* args[] = {(void*)&spec, (void*)&out, (void*)&gain, (void*)&g0};
  hipLaunchCooperativeKernel((void*)k_fused, dim3(grid), dim3(BLOCK),
                             args, 0, stream);
}

// Round 4
// 113.965 us; speedup vs baseline: 2.5421x; 2.5421x over previous
//
#include <hip/hip_runtime.h>

// spec (32, 4000, 161, 2) f32.
//   pow[b,t,k]  = re^2 + im^2
//   g0[b,t]     = sqrt((2*sum(pow) - pow[0] - pow[160]) / 320)
//   gain[b,t]   = EMA over t: c = 0.9c + 0.1*g0  (gain[b,0]=g0[b,0])
//   new_spec    = spec / (gain + 0.001)
// Outputs flat-concat: new_spec (41,216,000 f32) then gain (128,000 f32).

typedef float f32x4 __attribute__((ext_vector_type(4)));
typedef float f32x2 __attribute__((ext_vector_type(2)));

#define B_SZ 32
#define T_SZ 4000
#define FRAME_F 322            // floats per frame (161 bins * 2)
#define FRAMES (B_SZ * T_SZ)   // 128000
#define N_SPEC ((size_t)FRAMES * FRAME_F)  // 41,216,000
#define N4 (N_SPEC / 4)        // 10,304,000 (exact)
#define EMA_W 384              // 0.9^384 ~ 4e-18: below f32 resolution
#define BLOCK 256

// ---- K1: per-frame gain g0. Wave-per-frame, grid-stride. ----
__global__ __launch_bounds__(BLOCK) void k_frame_gain(
    const float* __restrict__ spec, float* __restrict__ g0) {
  int lane   = threadIdx.x & 63;
  int wave0  = (blockIdx.x * BLOCK + threadIdx.x) >> 6;
  int nwaves = (gridDim.x * BLOCK) >> 6;
#pragma unroll 2
  for (int wid = wave0; wid < FRAMES; wid += nwaves) {
    const float* fp = spec + (size_t)wid * FRAME_F;
    f32x4 v0 = *(const f32x4*)(fp + lane * 4);       // pairs 0..127
    float s0 = v0.x * v0.x + v0.y * v0.y;
    float s1 = v0.z * v0.z + v0.w * v0.w;
    float acc = 2.0f * (s0 + s1);
    if (lane == 0) acc -= s0;                        // pow[0] weight 1
    if (lane < 16) {                                 // pairs 128..159
      f32x4 v1 = *(const f32x4*)(fp + (64 + lane) * 4);
      acc += 2.0f * (v1.x * v1.x + v1.y * v1.y + v1.z * v1.z + v1.w * v1.w);
    } else if (lane == 16) {                         // pair 160, weight 1
      f32x2 v2 = *(const f32x2*)(fp + 320);
      acc += v2.x * v2.x + v2.y * v2.y;
    }
#pragma unroll
    for (int off = 32; off > 0; off >>= 1) acc += __shfl_xor(acc, off, 64);
    if (lane == 0) g0[wid] = sqrtf(acc * (1.0f / 320.0f));
  }
}

// ---- K2: EMA via truncated window (exact for t < EMA_W). ----
// Also emits inv = 1/(gain+1e-3) so K3's chain is load->mul->store.
__global__ __launch_bounds__(BLOCK) void k_ema(
    const float* __restrict__ g0, float* __restrict__ gain_out,
    float* __restrict__ inv_out) {
  __shared__ float xs[EMA_W + 256];
  int b  = blockIdx.y;
  int t0 = blockIdx.x * 256;
  int lo = t0 - (EMA_W - 1); if (lo < 0) lo = 0;
  int hi = t0 + 256; if (hi > T_SZ) hi = T_SZ;      // exclusive
  int n  = hi - lo;
  const float* gb = g0 + b * T_SZ;

  for (int i = threadIdx.x; i < n; i += BLOCK) xs[i] = gb[lo + i];
  __syncthreads();

  int t = t0 + (int)threadIdx.x;
  if (t >= T_SZ) return;
  int s = t - (EMA_W - 1); if (s < 1) s = 1;
  float c = (s == 1) ? xs[0] : 0.f;                  // lo==0 whenever s==1
  for (int k = s; k <= t; ++k) c = c * 0.9f + xs[k - lo] * 0.1f;
  gain_out[b * T_SZ + t] = c;
  inv_out[b * T_SZ + t]  = 1.0f / (c + 0.001f);
}

// ---- K3: out = spec * inv_gain, flat f32x4 grid-stride. ----
__global__ __launch_bounds__(BLOCK) void k_apply(
    const float* __restrict__ spec, const float* __restrict__ inv_g,
    float* __restrict__ out) {
  size_t stride = (size_t)gridDim.x * BLOCK;
#pragma unroll 2
  for (size_t i = (size_t)blockIdx.x * BLOCK + threadIdx.x; i < N4; i += stride) {
    f32x4 v = ((const f32x4*)spec)[i];
    unsigned p0 = (unsigned)(2 * i);                 // pair index of (v.x,v.y)
    unsigned f0 = p0 / 161u;                         // frame ids (magic mul)
    unsigned f1 = (p0 + 1) / 161u;
    float inv0 = inv_g[f0];
    float inv1 = inv_g[f1];
    f32x4 r;
    r.x = v.x * inv0; r.y = v.y * inv0;
    r.z = v.z * inv1; r.w = v.w * inv1;
    // nt store: don't pollute L2 with the write stream
    __builtin_nontemporal_store(r, (f32x4*)out + i);
  }
}

extern "C" void kernel_launch(void* const* d_in, const int* in_sizes, int n_in,
                              void* d_out, int out_size, void* d_ws, size_t ws_size,
                              hipStream_t stream) {
  const float* spec = (const float*)d_in[0];
  float* out   = (float*)d_out;
  float* gain  = out + N_SPEC;       // gain output lives in the d_out tail
  float* g0    = (float*)d_ws;       // 128000 f32
  float* inv_g = g0 + FRAMES;        // 128000 f32

  // K1: grid-stride, 4096 waves -> ~31 frames each
  k_frame_gain<<<1024, BLOCK, 0, stream>>>(spec, g0);

  // K2: one-shot (512 blocks)
  dim3 g2((T_SZ + 255) / 256, B_SZ);
  k_ema<<<g2, BLOCK, 0, stream>>>(g0, gain, inv_g);

  // K3: grid-stride, ~20 f32x4 per thread
  k_apply<<<2048, BLOCK, 0, stream>>>(spec, inv_g, out);
}

// Round 5
// 101.157 us; speedup vs baseline: 2.8640x; 1.1266x over previous
//
#include <hip/hip_runtime.h>

// spec (32, 4000, 161, 2) f32.
//   pow[b,t,k]  = re^2 + im^2
//   g0[b,t]     = sqrt((2*sum(pow) - pow[0] - pow[160]) / 320)
//   gain[b,t]   = EMA over t: c = 0.9c + 0.1*g0  (gain[b,0]=g0[b,0])
//   new_spec    = spec / (gain + 0.001)
// Outputs flat-concat: new_spec (41,216,000 f32) then gain (128,000 f32).

typedef float f32x4 __attribute__((ext_vector_type(4)));
typedef float f32x2 __attribute__((ext_vector_type(2)));

#define B_SZ 32
#define T_SZ 4000
#define FRAME_F 322            // floats per frame (161 bins * 2)
#define FRAMES (B_SZ * T_SZ)   // 128000
#define N_SPEC ((size_t)FRAMES * FRAME_F)  // 41,216,000
#define EMA_W 384              // 0.9^384 ~ 4e-18: below f32 resolution
#define HALO (EMA_W - 1)       // 383
#define BLOCK 256
#define CHUNK 100              // frames per fused block; 100*322/4 = 8050 f32x4 exact
#define CHUNKS_PER_B (T_SZ / CHUNK)  // 40
#define C4 (CHUNK * FRAME_F / 4)     // 8050

// ---- K1: per-frame gain g0. One 64-lane wave per frame, one-shot grid. ----
__global__ __launch_bounds__(BLOCK) void k_frame_gain(
    const float* __restrict__ spec, float* __restrict__ g0) {
  int gtid = blockIdx.x * BLOCK + threadIdx.x;
  int wid  = gtid >> 6;          // frame id
  int lane = threadIdx.x & 63;
  if (wid >= FRAMES) return;

  const float* fp = spec + (size_t)wid * FRAME_F;
  f32x4 v0 = *(const f32x4*)(fp + lane * 4);       // pairs 0..127
  float s0 = v0.x * v0.x + v0.y * v0.y;
  float s1 = v0.z * v0.z + v0.w * v0.w;
  float acc = 2.0f * (s0 + s1);
  if (lane == 0) acc -= s0;                        // pow[0] weight 1
  if (lane < 16) {                                 // pairs 128..159
    f32x4 v1 = *(const f32x4*)(fp + (64 + lane) * 4);
    acc += 2.0f * (v1.x * v1.x + v1.y * v1.y + v1.z * v1.z + v1.w * v1.w);
  } else if (lane == 16) {                         // pair 160, weight 1
    f32x2 v2 = *(const f32x2*)(fp + 320);
    acc += v2.x * v2.x + v2.y * v2.y;
  }
#pragma unroll
  for (int off = 32; off > 0; off >>= 1) acc += __shfl_xor(acc, off, 64);
  if (lane == 0) g0[wid] = sqrtf(acc * (1.0f / 320.0f));
}

// ---- K23: fused EMA (truncated window, exact for t < EMA_W) + apply. ----
// Block = (chunk c, batch b): frames t0..t0+99 of row b.
__global__ __launch_bounds__(BLOCK) void k_ema_apply(
    const float* __restrict__ spec, const float* __restrict__ g0,
    float* __restrict__ out, float* __restrict__ gain_out) {
  __shared__ float xs[HALO + CHUNK];   // staged g0 window (<= 483)
  __shared__ float inv_s[CHUNK];       // 1/(gain+1e-3) for this chunk

  int c  = blockIdx.x;
  int b  = blockIdx.y;
  int t0 = c * CHUNK;
  int lo = t0 - HALO; if (lo < 0) lo = 0;
  int n  = t0 + CHUNK - lo;            // <= 483
  int tid = threadIdx.x;

  const float* gb = g0 + b * T_SZ;
  for (int i = tid; i < n; i += BLOCK) xs[i] = gb[lo + i];
  __syncthreads();

  if (tid < CHUNK) {
    int t = t0 + tid;
    int s = t - HALO; if (s < 1) s = 1;
    float cc = (s == 1) ? xs[0] : 0.f;             // lo==0 whenever s==1
    for (int k = s; k <= t; ++k) cc = cc * 0.9f + xs[k - lo] * 0.1f;
    gain_out[b * T_SZ + t] = cc;
    inv_s[tid] = 1.0f / (cc + 0.001f);
  }
  __syncthreads();

  // Stream this chunk: 8050 f32x4, base exactly f32x4-aligned.
  size_t base4 = ((size_t)b * T_SZ + t0) * FRAME_F / 4;
  const f32x4* sp = (const f32x4*)spec + base4;
  f32x4*       op = (f32x4*)out  + base4;
#pragma unroll 4
  for (int i = tid; i < C4; i += BLOCK) {
    f32x4 v = sp[i];
    unsigned p0 = (unsigned)(2 * i);               // local pair idx of (v.x,v.y)
    unsigned lf = p0 / 161u;                       // local frame 0..99 (magic mul)
    unsigned r  = p0 - lf * 161u;
    unsigned lf1 = lf + (r == 160u);               // frame of second pair
    float i0 = inv_s[lf];
    float i1 = inv_s[lf1];
    f32x4 rr;
    rr.x = v.x * i0; rr.y = v.y * i0;
    rr.z = v.z * i1; rr.w = v.w * i1;
    // nt store: keep spec resident in L3, don't pollute L2 with writes
    __builtin_nontemporal_store(rr, op + i);
  }
}

extern "C" void kernel_launch(void* const* d_in, const int* in_sizes, int n_in,
                              void* d_out, int out_size, void* d_ws, size_t ws_size,
                              hipStream_t stream) {
  const float* spec = (const float*)d_in[0];
  float* out  = (float*)d_out;
  float* gain = out + N_SPEC;        // gain output lives in the d_out tail
  float* g0   = (float*)d_ws;        // 128000 f32 scratch

  // K1: one-shot, 4 frames (waves) per block
  int blocks1 = (FRAMES + 3) / 4;
  k_frame_gain<<<blocks1, BLOCK, 0, stream>>>(spec, g0);

  // K23: one-shot, (40 chunks) x (32 batch rows) = 1280 blocks
  dim3 g23(CHUNKS_PER_B, B_SZ);
  k_ema_apply<<<g23, BLOCK, 0, stream>>>(spec, g0, out, gain);
}